// Round 7
// baseline (146.028 us; speedup 1.0000x reference)
//
#include <hip/hip_runtime.h>
#include <hip/hip_bf16.h>
#include <stdint.h>

#define SS 4096
#define DD 256
#define HH 4
#define KK 64
#define ALPHA 0.18033688011112042f  // 0.125 * log2(e)

typedef float f32x4 __attribute__((ext_vector_type(4)));
typedef short s16x8 __attribute__((ext_vector_type(8)));
typedef unsigned int u32;

__device__ __forceinline__ unsigned short f2bf(float x) {
  union { float f; unsigned u; } v; v.f = x;
  unsigned r = v.u + 0x7fffu + ((v.u >> 16) & 1u);
  return (unsigned short)(r >> 16);
}

__device__ __forceinline__ u32 cvtpk(float lo, float hi) {
  u32 r;
  asm("v_cvt_pk_bf16_f32 %0, %1, %2" : "=v"(r) : "v"(lo), "v"(hi));
  return r;
}

__device__ __forceinline__ void gl_lds16(const unsigned short* g, unsigned short* l) {
  __builtin_amdgcn_global_load_lds(
      (const __attribute__((address_space(1))) u32*)g,
      (__attribute__((address_space(3))) u32*)l, 16, 0, 0);
}

// ---------------- Kernel 0: weight prep ----------------
__global__ void wprep(const float* __restrict__ Wq, const float* __restrict__ Wk,
                      const float* __restrict__ Wv, const float* __restrict__ Wo,
                      unsigned short* __restrict__ Wt, unsigned short* __restrict__ Wot)
{
  const int blk = blockIdx.x, t = threadIdx.x;
  const int rsub = t >> 4;
  const int c0 = (t & 15) * 16;
  if (blk < 48) {
    const int n = blk * 16 + rsub;               // 0..767
    const float* W = (n < 256) ? Wq : ((n < 512) ? Wk : Wv);
    const int nn = n & 255;
    const float sc = (n < 256) ? ALPHA : 1.0f;
    for (int c = c0; c < c0 + 16; ++c)
      Wt[(size_t)n * 256 + c] = f2bf(sc * W[(size_t)c * 256 + nn]);
  } else {
    const int d = (blk - 48) * 16 + rsub;        // 0..255
    for (int c = c0; c < c0 + 16; ++c)
      Wot[(size_t)d * 256 + c] = f2bf(Wo[(size_t)c * 256 + d]);
  }
}

// ---------------- Kernel 1: QKV projection (bf16 MFMA, no LDS) ----------------
__global__ __launch_bounds__(384, 3) void qkv_mfma(
    const float* __restrict__ query, const float* __restrict__ value,
    const unsigned short* __restrict__ Wt,
    const float* __restrict__ bq, const float* __restrict__ bk,
    const float* __restrict__ bv,
    unsigned short* __restrict__ qb, unsigned short* __restrict__ kbs,
    unsigned short* __restrict__ vts)
{
  const int t = threadIdx.x;
  const int w = t >> 6, l = t & 63, lr = l & 15, grp = l >> 4;
  const long r0 = (long)blockIdx.x * 32;
  const int n0 = w * 128;
  const int mat = w >> 1;

  const float* X = (mat == 0) ? query : value;

  f32x4 acc[2][8] = {};

  #pragma unroll 2
  for (int k0 = 0; k0 < 256; k0 += 32) {
    s16x8 bfr[2];
    #pragma unroll
    for (int mt = 0; mt < 2; ++mt) {
      const float* xp = X + (r0 + mt * 16 + lr) * 256 + k0 + grp * 8;
      f32x4 x0 = *(const f32x4*)xp;
      f32x4 x1 = *(const f32x4*)(xp + 4);
      union { u32 wd[4]; s16x8 v; } bb;
      bb.wd[0] = cvtpk(x0[0], x0[1]);
      bb.wd[1] = cvtpk(x0[2], x0[3]);
      bb.wd[2] = cvtpk(x1[0], x1[1]);
      bb.wd[3] = cvtpk(x1[2], x1[3]);
      bfr[mt] = bb.v;
    }
    if (mat == 2) {
      #pragma unroll
      for (int nt = 0; nt < 8; ++nt) {
        s16x8 af = *(const s16x8*)(Wt + (size_t)(n0 + nt * 16 + lr) * 256 + k0 + grp * 8);
        acc[0][nt] = __builtin_amdgcn_mfma_f32_16x16x32_bf16(bfr[0], af, acc[0][nt], 0, 0, 0);
        acc[1][nt] = __builtin_amdgcn_mfma_f32_16x16x32_bf16(bfr[1], af, acc[1][nt], 0, 0, 0);
      }
    } else {
      #pragma unroll
      for (int nt = 0; nt < 8; ++nt) {
        s16x8 af = *(const s16x8*)(Wt + (size_t)(n0 + nt * 16 + lr) * 256 + k0 + grp * 8);
        acc[0][nt] = __builtin_amdgcn_mfma_f32_16x16x32_bf16(af, bfr[0], acc[0][nt], 0, 0, 0);
        acc[1][nt] = __builtin_amdgcn_mfma_f32_16x16x32_bf16(af, bfr[1], acc[1][nt], 0, 0, 0);
      }
    }
  }

  const int b   = (int)(r0 >> 12);
  const int s0  = (int)(r0 & 4095);
  const int nl  = n0 & 255;
  const int kt  = s0 >> 6;
  const int kvb = s0 & 63;

  if (mat == 2) {
    #pragma unroll
    for (int nt = 0; nt < 8; ++nt) {
      const int n = nl + nt * 16 + lr;
      const int h = n >> 6;
      const int dk0 = n & 63;
      const int m2 = dk0 >> 4, lrv = dk0 & 15;
      const float bvn = bv[n];
      const size_t base = (size_t)(b * 4 + h) * (SS * KK) + (size_t)kt * 4096;
      const int cb = (m2 * 2 + ((kvb >> 5) & 1)) * 64 + grp * 16 + lrv;
      #pragma unroll
      for (int mt = 0; mt < 2; ++mt) {
        f32x4 o = acc[mt][nt] + bvn;
        uint2 pk2; pk2.x = cvtpk(o[0], o[1]); pk2.y = cvtpk(o[2], o[3]);
        *(uint2*)&vts[base + (size_t)cb * 8 + mt * 4] = pk2;
      }
    }
  } else {
    #pragma unroll
    for (int nt = 0; nt < 8; ++nt) {
      const int n = nl + nt * 16 + grp * 4;   // within-matrix 0..255, mult of 4
      const int h = n >> 6;
      if (mat == 0) {
        f32x4 bias = *(const f32x4*)&bq[n] * ALPHA;
        #pragma unroll
        for (int mt = 0; mt < 2; ++mt) {
          const int s = s0 + mt * 16 + lr;
          f32x4 o = acc[mt][nt] + bias;
          uint2 pk2; pk2.x = cvtpk(o[0], o[1]); pk2.y = cvtpk(o[2], o[3]);
          *(uint2*)&qb[((size_t)(b * 4 + h) * SS + s) * KK + (n & 63)] = pk2;
        }
      } else {
        const int d0 = n & 63;
        const int cc = d0 >> 5, grpk = (d0 & 31) >> 3, jlo = d0 & 7;
        f32x4 bias = *(const f32x4*)&bk[n];
        const size_t base = (size_t)(b * 4 + h) * (SS * KK) + (size_t)kt * 4096;
        #pragma unroll
        for (int mt = 0; mt < 2; ++mt) {
          const int kv = kvb + mt * 16 + lr;
          const int chunk = (((kv >> 4) * 2 + cc) * 4 + grpk) * 16 + (kv & 15);
          f32x4 o = acc[mt][nt] + bias;
          uint2 pk2; pk2.x = cvtpk(o[0], o[1]); pk2.y = cvtpk(o[2], o[3]);
          *(uint2*)&kbs[base + chunk * 8 + jlo] = pk2;
        }
      }
    }
  }
}

// ---------------- Kernel 2: causal flash attention ----------------
// 512 blocks x 256 thr (4 waves x 32 q-rows = 128-row supertile/block),
// 32 KB LDS dbuf (64-row KV tiles) -> 2 blocks/CU, 8 waves/CU (2/SIMD).
// Balanced mapping: sup(i)+sup(i^1)=31 and sup(i)+sup(i+256)=31, so the two
// co-resident blocks on a CU total ~66 tile-steps under either linear-fill
// or round-robin placement (perf heuristic only; correctness placement-free).
// Fixed-max exp2 softmax (P=exp2(score-16)); row-sum l via ones-MFMA.
__global__ __launch_bounds__(256, 2) void attn(
    const unsigned short* __restrict__ qb,
    const unsigned short* __restrict__ kbs,
    const unsigned short* __restrict__ vts,
    unsigned short* __restrict__ ctxb)
{
  __shared__ __align__(16) unsigned short Kl[2][4096];
  __shared__ __align__(16) unsigned short Vl[2][4096];

  const int t = threadIdx.x;
  const int w = t >> 6, l = t & 63, lr = l & 15, grp = l >> 4;

  const int i   = blockIdx.x;
  const int p   = (i ^ (i >> 8)) & 1;
  const int m   = (i >> 4) & 15;
  const int sup = p ? (31 - m) : m;                       // 0..31
  const int bh  = ((i >> 1) & 7) | (((i >> 8) & 1) << 3); // 0..15
  const int b = bh >> 2, h = bh & 3;

  const unsigned short* kbase = kbs + (size_t)bh * (SS * KK);
  const unsigned short* vbase = vts + (size_t)bh * (SS * KK);
  const unsigned short* qpb   = qb  + (size_t)bh * (SS * KK);

  const int row0 = sup * 128;
  const int wrow = row0 + w * 32;

  s16x8 qf[2][2];
  #pragma unroll
  for (int q2 = 0; q2 < 2; ++q2) {
    const unsigned short* qp = qpb + (size_t)(wrow + q2 * 16 + lr) * KK;
    qf[q2][0] = *(const s16x8*)(qp + grp * 8);
    qf[q2][1] = *(const s16x8*)(qp + 32 + grp * 8);
  }

  s16x8 ones;
  #pragma unroll
  for (int e = 0; e < 8; ++e) ones[e] = (short)0x3F80;   // bf16 1.0
  const f32x4 minit = {-16.f, -16.f, -16.f, -16.f};

  f32x4 cacc[2][4] = {};
  f32x4 lacc[2] = {};

  const int off0 = (w * 64 + l) * 8;
  const int off1 = ((4 + w) * 64 + l) * 8;

  // prologue: stage KV tile 0 -> buf 0 (identity chunk map)
  gl_lds16(kbase + off0, &Kl[0][w * 512]);
  gl_lds16(kbase + off1, &Kl[0][(4 + w) * 512]);
  gl_lds16(vbase + off0, &Vl[0][w * 512]);
  gl_lds16(vbase + off1, &Vl[0][(4 + w) * 512]);
  __syncthreads();

  const int ktmax = 2 * sup + 1;

  for (int kt = 0; kt <= ktmax; ++kt) {
    const int cur = kt & 1;
    if (kt < ktmax) {
      const unsigned short* ks = kbase + (size_t)(kt + 1) * 4096;
      const unsigned short* vs = vbase + (size_t)(kt + 1) * 4096;
      unsigned short* Kd = &Kl[cur ^ 1][0];
      unsigned short* Vd = &Vl[cur ^ 1][0];
      gl_lds16(ks + off0, Kd + w * 512);
      gl_lds16(ks + off1, Kd + (4 + w) * 512);
      gl_lds16(vs + off0, Vd + w * 512);
      gl_lds16(vs + off1, Vd + (4 + w) * 512);
    }

    // final KV tile is fully masked for waves 0,1 -> exact skip (wave-uniform)
    if (!(kt == ktmax && w < 2)) {
      const unsigned short* Kb = &Kl[cur][0];
      const unsigned short* Vb = &Vl[cur][0];

      s16x8 kf[8];
      #pragma unroll
      for (int kc = 0; kc < 8; ++kc)
        kf[kc] = *(const s16x8*)&Kb[((kc * 4 + grp) * 16 + lr) * 8];

      // QK^T: S^T layout D[kv][q]; C-init = -16 folds the constant max
      f32x4 sc[2][4];
      #pragma unroll
      for (int q2 = 0; q2 < 2; ++q2) {
        #pragma unroll
        for (int kvt = 0; kvt < 4; ++kvt) {
          f32x4 a = __builtin_amdgcn_mfma_f32_16x16x32_bf16(kf[kvt * 2 + 0], qf[q2][0], minit, 0, 0, 0);
          a = __builtin_amdgcn_mfma_f32_16x16x32_bf16(kf[kvt * 2 + 1], qf[q2][1], a, 0, 0, 0);
          sc[q2][kvt] = a;
        }
      }

      // causal mask only on diagonal-range tiles (global indices)
      if (kt >= 2 * sup) {
        const int kvb0 = kt * 64;
        #pragma unroll
        for (int q2 = 0; q2 < 2; ++q2) {
          const int qrow = wrow + q2 * 16 + lr;
          #pragma unroll
          for (int kvt = 0; kvt < 4; ++kvt)
            #pragma unroll
            for (int e = 0; e < 4; ++e)
              if ((kvb0 + kvt * 16 + grp * 4 + e) > qrow) sc[q2][kvt][e] += -1.0e9f;
        }
      }

      #pragma unroll
      for (int q2 = 0; q2 < 2; ++q2)
        #pragma unroll
        for (int kvt = 0; kvt < 4; ++kvt)
          #pragma unroll
          for (int e = 0; e < 4; ++e)
            sc[q2][kvt][e] = exp2f(sc[q2][kvt][e]);

      s16x8 pf[2][2];
      #pragma unroll
      for (int q2 = 0; q2 < 2; ++q2) {
        #pragma unroll
        for (int kap = 0; kap < 2; ++kap) {
          union { u32 wd[4]; s16x8 v; } pu;
          pu.wd[0] = cvtpk(sc[q2][2 * kap][0], sc[q2][2 * kap][1]);
          pu.wd[1] = cvtpk(sc[q2][2 * kap][2], sc[q2][2 * kap][3]);
          pu.wd[2] = cvtpk(sc[q2][2 * kap + 1][0], sc[q2][2 * kap + 1][1]);
          pu.wd[3] = cvtpk(sc[q2][2 * kap + 1][2], sc[q2][2 * kap + 1][3]);
          pf[q2][kap] = pu.v;
        }
      }

      // PV: V frags shared across both q-tiles
      #pragma unroll
      for (int m2 = 0; m2 < 4; ++m2) {
        #pragma unroll
        for (int kap = 0; kap < 2; ++kap) {
          s16x8 vfr = *(const s16x8*)&Vb[((m2 * 2 + kap) * 64 + l) * 8];
          cacc[0][m2] = __builtin_amdgcn_mfma_f32_16x16x32_bf16(vfr, pf[0][kap], cacc[0][m2], 0, 0, 0);
          cacc[1][m2] = __builtin_amdgcn_mfma_f32_16x16x32_bf16(vfr, pf[1][kap], cacc[1][m2], 0, 0, 0);
        }
      }
      #pragma unroll
      for (int q2 = 0; q2 < 2; ++q2) {
        lacc[q2] = __builtin_amdgcn_mfma_f32_16x16x32_bf16(ones, pf[q2][0], lacc[q2], 0, 0, 0);
        lacc[q2] = __builtin_amdgcn_mfma_f32_16x16x32_bf16(ones, pf[q2][1], lacc[q2], 0, 0, 0);
      }
    }
    __syncthreads();
  }

  // epilogue
  #pragma unroll
  for (int q2 = 0; q2 < 2; ++q2) {
    const float inv = 1.0f / lacc[q2][0];
    unsigned short* crow = ctxb + ((size_t)b * SS + wrow + q2 * 16 + lr) * DD + h * KK;
    #pragma unroll
    for (int m2 = 0; m2 < 4; ++m2) {
      f32x4 o = cacc[q2][m2] * inv;
      uint2 pk2; pk2.x = cvtpk(o[0], o[1]); pk2.y = cvtpk(o[2], o[3]);
      *(uint2*)&crow[m2 * 16 + grp * 4] = pk2;
    }
  }
}

// ---------------- Kernel 3: output projection + residual + LayerNorm (MFMA) ----------------
__global__ __launch_bounds__(256, 4) void oproj_ln(
    const unsigned short* __restrict__ ctxb, const unsigned short* __restrict__ Wot,
    const float* __restrict__ bo, const float* __restrict__ query,
    const float* __restrict__ gamma, const float* __restrict__ beta,
    float* __restrict__ out)
{
  __shared__ __align__(16) float redS[32][4];
  __shared__ __align__(16) float redQ[32][4];

  const int t = threadIdx.x;
  const int w = t >> 6, l = t & 63, lr = l & 15, grp = l >> 4;
  const long r0 = (long)blockIdx.x * 32;
  const int n0 = w * 64;

  f32x4 acc[2][4] = {};

  #pragma unroll 2
  for (int k0 = 0; k0 < 256; k0 += 32) {
    s16x8 bfr[2];
    #pragma unroll
    for (int mt = 0; mt < 2; ++mt)
      bfr[mt] = *(const s16x8*)(ctxb + (size_t)(r0 + mt * 16 + lr) * 256 + k0 + grp * 8);
    #pragma unroll
    for (int nt = 0; nt < 4; ++nt) {
      s16x8 af = *(const s16x8*)(Wot + (size_t)(n0 + nt * 16 + lr) * 256 + k0 + grp * 8);
      acc[0][nt] = __builtin_amdgcn_mfma_f32_16x16x32_bf16(af, bfr[0], acc[0][nt], 0, 0, 0);
      acc[1][nt] = __builtin_amdgcn_mfma_f32_16x16x32_bf16(af, bfr[1], acc[1][nt], 0, 0, 0);
    }
  }

  float sm[2] = {0.f, 0.f}, sq[2] = {0.f, 0.f};
  #pragma unroll
  for (int mt = 0; mt < 2; ++mt) {
    const long s = r0 + mt * 16 + lr;
    #pragma unroll
    for (int nt = 0; nt < 4; ++nt) {
      const int n = n0 + nt * 16 + grp * 4;
      f32x4 v = acc[mt][nt] + *(const f32x4*)&bo[n] + *(const f32x4*)&query[s * 256 + n];
      acc[mt][nt] = v;
      sm[mt] += v[0] + v[1] + v[2] + v[3];
      sq[mt] += v[0]*v[0] + v[1]*v[1] + v[2]*v[2] + v[3]*v[3];
    }
    sm[mt] += __shfl_xor(sm[mt], 16); sm[mt] += __shfl_xor(sm[mt], 32);
    sq[mt] += __shfl_xor(sq[mt], 16); sq[mt] += __shfl_xor(sq[mt], 32);
  }
  if (grp == 0) {
    redS[0 * 16 + lr][w] = sm[0]; redQ[0 * 16 + lr][w] = sq[0];
    redS[1 * 16 + lr][w] = sm[1]; redQ[1 * 16 + lr][w] = sq[1];
  }
  __syncthreads();

  #pragma unroll
  for (int mt = 0; mt < 2; ++mt) {
    f32x4 s4 = *(const f32x4*)&redS[mt * 16 + lr][0];
    f32x4 q4 = *(const f32x4*)&redQ[mt * 16 + lr][0];
    const float tot = s4[0] + s4[1] + s4[2] + s4[3];
    const float tq  = q4[0] + q4[1] + q4[2] + q4[3];
    const float mu  = tot * 0.00390625f;
    const float var = tq * 0.00390625f - mu * mu;
    const float rs  = rsqrtf(var + 1.0e-3f);
    const long s = r0 + mt * 16 + lr;
    #pragma unroll
    for (int nt = 0; nt < 4; ++nt) {
      const int n = n0 + nt * 16 + grp * 4;
      f32x4 g = *(const f32x4*)&gamma[n];
      f32x4 bt = *(const f32x4*)&beta[n];
      f32x4 o = (acc[mt][nt] - mu) * rs * g + bt;
      *(f32x4*)&out[s * 256 + n] = o;
    }
  }
}

extern "C" void kernel_launch(void* const* d_in, const int* in_sizes, int n_in,
                              void* d_out, int out_size, void* d_ws, size_t ws_size,
                              hipStream_t stream) {
  const float* query = (const float*)d_in[0];
  const float* value = (const float*)d_in[1];
  const float* Wq    = (const float*)d_in[2];
  const float* bq    = (const float*)d_in[3];
  const float* Wk    = (const float*)d_in[4];
  const float* bk    = (const float*)d_in[5];
  const float* Wv    = (const float*)d_in[6];
  const float* bv    = (const float*)d_in[7];
  const float* Wo    = (const float*)d_in[8];
  const float* bo    = (const float*)d_in[9];
  const float* gamma = (const float*)d_in[10];
  const float* beta  = (const float*)d_in[11];
  float* out = (float*)d_out;

  char* ws = (char*)d_ws;
  unsigned short* qb   = (unsigned short*)ws;                         // 8 MiB bf16 [bh][s][dk] (alpha-scaled)
  unsigned short* kbs  = (unsigned short*)(ws + ((size_t)8  << 20));  // 8 MiB bf16 chunked K
  unsigned short* vts  = (unsigned short*)(ws + ((size_t)16 << 20));  // 8 MiB bf16 chunked V^T
  unsigned short* ctxb = (unsigned short*)(ws + ((size_t)24 << 20));  // 8 MiB bf16 [b][s][hk]
  unsigned short* Wt   = (unsigned short*)(ws + ((size_t)32 << 20));  // 384 KiB bf16 [768][256]
  unsigned short* Wot  = Wt + (size_t)768 * 256;                      // 128 KiB bf16 [256][256]

  wprep<<<64, 256, 0, stream>>>(Wq, Wk, Wv, Wo, Wt, Wot);
  qkv_mfma<<<512, 384, 0, stream>>>(query, value, Wt, bq, bk, bv, qb, kbs, vts);
  attn<<<512, 256, 0, stream>>>(qb, kbs, vts, ctxb);
  oproj_ln<<<512, 256, 0, stream>>>(ctxb, Wot, bo, query, gamma, beta, out);
}

// Round 8
// 139.143 us; speedup vs baseline: 1.0495x; 1.0495x over previous
//
#include <hip/hip_runtime.h>
#include <hip/hip_bf16.h>
#include <stdint.h>

#define SS 4096
#define DD 256
#define HH 4
#define KK 64
#define ALPHA 0.18033688011112042f  // 0.125 * log2(e)

typedef float f32x4 __attribute__((ext_vector_type(4)));
typedef short s16x8 __attribute__((ext_vector_type(8)));
typedef unsigned int u32;

__device__ __forceinline__ unsigned short f2bf(float x) {
  union { float f; unsigned u; } v; v.f = x;
  unsigned r = v.u + 0x7fffu + ((v.u >> 16) & 1u);
  return (unsigned short)(r >> 16);
}

__device__ __forceinline__ u32 cvtpk(float lo, float hi) {
  u32 r;
  asm("v_cvt_pk_bf16_f32 %0, %1, %2" : "=v"(r) : "v"(lo), "v"(hi));
  return r;
}

__device__ __forceinline__ void gl_lds16(const unsigned short* g, unsigned short* l) {
  __builtin_amdgcn_global_load_lds(
      (const __attribute__((address_space(1))) u32*)g,
      (__attribute__((address_space(3))) u32*)l, 16, 0, 0);
}

// ---------------- Kernel 0: weight prep ----------------
__global__ void wprep(const float* __restrict__ Wq, const float* __restrict__ Wk,
                      const float* __restrict__ Wv, const float* __restrict__ Wo,
                      unsigned short* __restrict__ Wt, unsigned short* __restrict__ Wot)
{
  const int blk = blockIdx.x, t = threadIdx.x;
  const int rsub = t >> 4;
  const int c0 = (t & 15) * 16;
  if (blk < 48) {
    const int n = blk * 16 + rsub;               // 0..767
    const float* W = (n < 256) ? Wq : ((n < 512) ? Wk : Wv);
    const int nn = n & 255;
    const float sc = (n < 256) ? ALPHA : 1.0f;
    for (int c = c0; c < c0 + 16; ++c)
      Wt[(size_t)n * 256 + c] = f2bf(sc * W[(size_t)c * 256 + nn]);
  } else {
    const int d = (blk - 48) * 16 + rsub;        // 0..255
    for (int c = c0; c < c0 + 16; ++c)
      Wot[(size_t)d * 256 + c] = f2bf(Wo[(size_t)c * 256 + d]);
  }
}

// ---------------- Kernel 1: QKV projection (bf16 MFMA, no LDS) ----------------
__global__ __launch_bounds__(384, 3) void qkv_mfma(
    const float* __restrict__ query, const float* __restrict__ value,
    const unsigned short* __restrict__ Wt,
    const float* __restrict__ bq, const float* __restrict__ bk,
    const float* __restrict__ bv,
    unsigned short* __restrict__ qb, unsigned short* __restrict__ kbs,
    unsigned short* __restrict__ vts)
{
  const int t = threadIdx.x;
  const int w = t >> 6, l = t & 63, lr = l & 15, grp = l >> 4;
  const long r0 = (long)blockIdx.x * 32;
  const int n0 = w * 128;
  const int mat = w >> 1;

  const float* X = (mat == 0) ? query : value;

  f32x4 acc[2][8] = {};

  #pragma unroll 2
  for (int k0 = 0; k0 < 256; k0 += 32) {
    s16x8 bfr[2];
    #pragma unroll
    for (int mt = 0; mt < 2; ++mt) {
      const float* xp = X + (r0 + mt * 16 + lr) * 256 + k0 + grp * 8;
      f32x4 x0 = *(const f32x4*)xp;
      f32x4 x1 = *(const f32x4*)(xp + 4);
      union { u32 wd[4]; s16x8 v; } bb;
      bb.wd[0] = cvtpk(x0[0], x0[1]);
      bb.wd[1] = cvtpk(x0[2], x0[3]);
      bb.wd[2] = cvtpk(x1[0], x1[1]);
      bb.wd[3] = cvtpk(x1[2], x1[3]);
      bfr[mt] = bb.v;
    }
    if (mat == 2) {
      #pragma unroll
      for (int nt = 0; nt < 8; ++nt) {
        s16x8 af = *(const s16x8*)(Wt + (size_t)(n0 + nt * 16 + lr) * 256 + k0 + grp * 8);
        acc[0][nt] = __builtin_amdgcn_mfma_f32_16x16x32_bf16(bfr[0], af, acc[0][nt], 0, 0, 0);
        acc[1][nt] = __builtin_amdgcn_mfma_f32_16x16x32_bf16(bfr[1], af, acc[1][nt], 0, 0, 0);
      }
    } else {
      #pragma unroll
      for (int nt = 0; nt < 8; ++nt) {
        s16x8 af = *(const s16x8*)(Wt + (size_t)(n0 + nt * 16 + lr) * 256 + k0 + grp * 8);
        acc[0][nt] = __builtin_amdgcn_mfma_f32_16x16x32_bf16(af, bfr[0], acc[0][nt], 0, 0, 0);
        acc[1][nt] = __builtin_amdgcn_mfma_f32_16x16x32_bf16(af, bfr[1], acc[1][nt], 0, 0, 0);
      }
    }
  }

  const int b   = (int)(r0 >> 12);
  const int s0  = (int)(r0 & 4095);
  const int nl  = n0 & 255;
  const int kt  = s0 >> 6;
  const int kvb = s0 & 63;

  if (mat == 2) {
    #pragma unroll
    for (int nt = 0; nt < 8; ++nt) {
      const int n = nl + nt * 16 + lr;
      const int h = n >> 6;
      const int dk0 = n & 63;
      const int m2 = dk0 >> 4, lrv = dk0 & 15;
      const float bvn = bv[n];
      const size_t base = (size_t)(b * 4 + h) * (SS * KK) + (size_t)kt * 4096;
      const int cb = (m2 * 2 + ((kvb >> 5) & 1)) * 64 + grp * 16 + lrv;
      #pragma unroll
      for (int mt = 0; mt < 2; ++mt) {
        f32x4 o = acc[mt][nt] + bvn;
        uint2 pk2; pk2.x = cvtpk(o[0], o[1]); pk2.y = cvtpk(o[2], o[3]);
        *(uint2*)&vts[base + (size_t)cb * 8 + mt * 4] = pk2;
      }
    }
  } else {
    #pragma unroll
    for (int nt = 0; nt < 8; ++nt) {
      const int n = nl + nt * 16 + grp * 4;   // within-matrix 0..255, mult of 4
      const int h = n >> 6;
      if (mat == 0) {
        f32x4 bias = *(const f32x4*)&bq[n] * ALPHA;
        #pragma unroll
        for (int mt = 0; mt < 2; ++mt) {
          const int s = s0 + mt * 16 + lr;
          f32x4 o = acc[mt][nt] + bias;
          uint2 pk2; pk2.x = cvtpk(o[0], o[1]); pk2.y = cvtpk(o[2], o[3]);
          *(uint2*)&qb[((size_t)(b * 4 + h) * SS + s) * KK + (n & 63)] = pk2;
        }
      } else {
        const int d0 = n & 63;
        const int cc = d0 >> 5, grpk = (d0 & 31) >> 3, jlo = d0 & 7;
        f32x4 bias = *(const f32x4*)&bk[n];
        const size_t base = (size_t)(b * 4 + h) * (SS * KK) + (size_t)kt * 4096;
        #pragma unroll
        for (int mt = 0; mt < 2; ++mt) {
          const int kv = kvb + mt * 16 + lr;
          const int chunk = (((kv >> 4) * 2 + cc) * 4 + grpk) * 16 + (kv & 15);
          f32x4 o = acc[mt][nt] + bias;
          uint2 pk2; pk2.x = cvtpk(o[0], o[1]); pk2.y = cvtpk(o[2], o[3]);
          *(uint2*)&kbs[base + chunk * 8 + jlo] = pk2;
        }
      }
    }
  }
}

// ---------------- Kernel 2: causal flash attention (KV-split, exact balance) ----------------
// 512 blocks x 256 thr (4 waves x 32 q-rows). bh = i&15, pr = (i>>4)&15, role = i>>8.
// role 0 (light): supertile pr complete (2pr+2 tiles) then supertile 31-pr
//   tiles [0, 31-2pr) -> slot 0.  role 1 (heavy): supertile 31-pr tiles
//   [31-2pr, 64-2pr) -> slot 1.  EVERY block = exactly 33 tile-steps.
// Fixed-max softmax P=exp2(s-16): partial (num,l) from disjoint KV ranges
// simply ADD (same constant max) -> no m-merge. num fp32, combined in oproj.
__global__ __launch_bounds__(256, 2) void attn(
    const unsigned short* __restrict__ qb,
    const unsigned short* __restrict__ kbs,
    const unsigned short* __restrict__ vts,
    float* __restrict__ num0, float* __restrict__ num1,
    float* __restrict__ lb0, float* __restrict__ lb1)
{
  __shared__ __align__(16) unsigned short Kl[2][4096];
  __shared__ __align__(16) unsigned short Vl[2][4096];

  const int t = threadIdx.x;
  const int w = t >> 6, l = t & 63, lr = l & 15, grp = l >> 4;

  const int i    = blockIdx.x;
  const int bh   = i & 15;
  const int pr   = (i >> 4) & 15;
  const int role = i >> 8;
  const int b = bh >> 2, h = bh & 3;
  const int phA_last = 2 * pr + 1;   // role 0 phase-A last step

  const unsigned short* kbase = kbs + (size_t)bh * (SS * KK);
  const unsigned short* vbase = vts + (size_t)bh * (SS * KK);
  const unsigned short* qpb   = qb  + (size_t)bh * (SS * KK);

  int sup = (role == 0) ? pr : (31 - pr);

  s16x8 qf[2][2];
  #pragma unroll
  for (int q2 = 0; q2 < 2; ++q2) {
    const unsigned short* qp = qpb + (size_t)(sup * 128 + w * 32 + q2 * 16 + lr) * KK;
    qf[q2][0] = *(const s16x8*)(qp + grp * 8);
    qf[q2][1] = *(const s16x8*)(qp + 32 + grp * 8);
  }

  s16x8 ones;
  #pragma unroll
  for (int e = 0; e < 8; ++e) ones[e] = (short)0x3F80;   // bf16 1.0
  const f32x4 minit = {-16.f, -16.f, -16.f, -16.f};

  f32x4 cacc[2][4] = {};
  f32x4 lacc[2] = {};

  const int off0 = (w * 64 + l) * 8;
  const int off1 = ((4 + w) * 64 + l) * 8;

  // prologue: stage first tile
  {
    const int kt0 = (role == 0) ? 0 : (31 - 2 * pr);
    const unsigned short* ks = kbase + (size_t)kt0 * 4096;
    const unsigned short* vs = vbase + (size_t)kt0 * 4096;
    gl_lds16(ks + off0, &Kl[0][w * 512]);
    gl_lds16(ks + off1, &Kl[0][(4 + w) * 512]);
    gl_lds16(vs + off0, &Vl[0][w * 512]);
    gl_lds16(vs + off1, &Vl[0][(4 + w) * 512]);
  }
  __syncthreads();

  for (int ss = 0; ss <= 32; ++ss) {
    const int cur = ss & 1;
    const int kt = (role == 0)
        ? ((ss <= phA_last) ? ss : (ss - (phA_last + 1)))
        : (31 - 2 * pr + ss);

    if (ss < 32) {
      const int ktn = (role == 0)
          ? ((ss + 1 <= phA_last) ? (ss + 1) : (ss + 1 - (phA_last + 1)))
          : (31 - 2 * pr + ss + 1);
      const unsigned short* ks = kbase + (size_t)ktn * 4096;
      const unsigned short* vs = vbase + (size_t)ktn * 4096;
      unsigned short* Kd = &Kl[cur ^ 1][0];
      unsigned short* Vd = &Vl[cur ^ 1][0];
      gl_lds16(ks + off0, Kd + w * 512);
      gl_lds16(ks + off1, Kd + (4 + w) * 512);
      gl_lds16(vs + off0, Vd + w * 512);
      gl_lds16(vs + off1, Vd + (4 + w) * 512);
    }

    // kt == 2*sup+1 is fully masked for waves 0,1 -> exact skip
    if (!(kt == 2 * sup + 1 && w < 2)) {
      const unsigned short* Kb = &Kl[cur][0];
      const unsigned short* Vb = &Vl[cur][0];

      s16x8 kf[8];
      #pragma unroll
      for (int kc = 0; kc < 8; ++kc)
        kf[kc] = *(const s16x8*)&Kb[((kc * 4 + grp) * 16 + lr) * 8];

      // QK^T: S^T layout D[kv][q]; C-init = -16 folds the constant max
      f32x4 sc[2][4];
      #pragma unroll
      for (int q2 = 0; q2 < 2; ++q2) {
        #pragma unroll
        for (int kvt = 0; kvt < 4; ++kvt) {
          f32x4 a = __builtin_amdgcn_mfma_f32_16x16x32_bf16(kf[kvt * 2 + 0], qf[q2][0], minit, 0, 0, 0);
          a = __builtin_amdgcn_mfma_f32_16x16x32_bf16(kf[kvt * 2 + 1], qf[q2][1], a, 0, 0, 0);
          sc[q2][kvt] = a;
        }
      }

      // causal mask only on diagonal-range tiles
      if (kt >= 2 * sup) {
        const int kvb0 = kt * 64;
        #pragma unroll
        for (int q2 = 0; q2 < 2; ++q2) {
          const int qrow = sup * 128 + w * 32 + q2 * 16 + lr;
          #pragma unroll
          for (int kvt = 0; kvt < 4; ++kvt)
            #pragma unroll
            for (int e = 0; e < 4; ++e)
              if ((kvb0 + kvt * 16 + grp * 4 + e) > qrow) sc[q2][kvt][e] += -1.0e9f;
        }
      }

      #pragma unroll
      for (int q2 = 0; q2 < 2; ++q2)
        #pragma unroll
        for (int kvt = 0; kvt < 4; ++kvt)
          #pragma unroll
          for (int e = 0; e < 4; ++e)
            sc[q2][kvt][e] = exp2f(sc[q2][kvt][e]);

      s16x8 pf[2][2];
      #pragma unroll
      for (int q2 = 0; q2 < 2; ++q2) {
        #pragma unroll
        for (int kap = 0; kap < 2; ++kap) {
          union { u32 wd[4]; s16x8 v; } pu;
          pu.wd[0] = cvtpk(sc[q2][2 * kap][0], sc[q2][2 * kap][1]);
          pu.wd[1] = cvtpk(sc[q2][2 * kap][2], sc[q2][2 * kap][3]);
          pu.wd[2] = cvtpk(sc[q2][2 * kap + 1][0], sc[q2][2 * kap + 1][1]);
          pu.wd[3] = cvtpk(sc[q2][2 * kap + 1][2], sc[q2][2 * kap + 1][3]);
          pf[q2][kap] = pu.v;
        }
      }

      // PV + row-sum (ones-MFMA); V frags shared across both q-tiles
      #pragma unroll
      for (int m2 = 0; m2 < 4; ++m2) {
        #pragma unroll
        for (int kap = 0; kap < 2; ++kap) {
          s16x8 vfr = *(const s16x8*)&Vb[((m2 * 2 + kap) * 64 + l) * 8];
          cacc[0][m2] = __builtin_amdgcn_mfma_f32_16x16x32_bf16(vfr, pf[0][kap], cacc[0][m2], 0, 0, 0);
          cacc[1][m2] = __builtin_amdgcn_mfma_f32_16x16x32_bf16(vfr, pf[1][kap], cacc[1][m2], 0, 0, 0);
        }
      }
      #pragma unroll
      for (int q2 = 0; q2 < 2; ++q2) {
        lacc[q2] = __builtin_amdgcn_mfma_f32_16x16x32_bf16(ones, pf[q2][0], lacc[q2], 0, 0, 0);
        lacc[q2] = __builtin_amdgcn_mfma_f32_16x16x32_bf16(ones, pf[q2][1], lacc[q2], 0, 0, 0);
      }
    }

    // role-0 phase switch: write light supertile (slot 0), move to 31-pr
    if (role == 0 && ss == phA_last) {
      #pragma unroll
      for (int q2 = 0; q2 < 2; ++q2) {
        const int rowg = sup * 128 + w * 32 + q2 * 16 + lr;
        float* np_ = num0 + ((size_t)((b << 12) + rowg)) * 256 + h * 64;
        #pragma unroll
        for (int m2 = 0; m2 < 4; ++m2) {
          *(f32x4*)&np_[m2 * 16 + grp * 4] = cacc[q2][m2];
          cacc[q2][m2] = (f32x4){0.f, 0.f, 0.f, 0.f};
        }
        if (grp == 0) lb0[(bh << 12) + rowg] = lacc[q2][0];
        lacc[q2] = (f32x4){0.f, 0.f, 0.f, 0.f};
      }
      sup = 31 - pr;
      #pragma unroll
      for (int q2 = 0; q2 < 2; ++q2) {
        const unsigned short* qp = qpb + (size_t)(sup * 128 + w * 32 + q2 * 16 + lr) * KK;
        qf[q2][0] = *(const s16x8*)(qp + grp * 8);
        qf[q2][1] = *(const s16x8*)(qp + 32 + grp * 8);
      }
    }
    __syncthreads();
  }

  // final epilogue: role 0 -> slot 0, role 1 -> slot 1 (heavy rows only)
  if (role == 0) {
    #pragma unroll
    for (int q2 = 0; q2 < 2; ++q2) {
      const int rowg = sup * 128 + w * 32 + q2 * 16 + lr;
      float* np_ = num0 + ((size_t)((b << 12) + rowg)) * 256 + h * 64;
      #pragma unroll
      for (int m2 = 0; m2 < 4; ++m2)
        *(f32x4*)&np_[m2 * 16 + grp * 4] = cacc[q2][m2];
      if (grp == 0) lb0[(bh << 12) + rowg] = lacc[q2][0];
    }
  } else {
    #pragma unroll
    for (int q2 = 0; q2 < 2; ++q2) {
      const int rowg = sup * 128 + w * 32 + q2 * 16 + lr;   // >= 2048
      float* np_ = num1 + ((size_t)((b << 11) + (rowg - 2048))) * 256 + h * 64;
      #pragma unroll
      for (int m2 = 0; m2 < 4; ++m2)
        *(f32x4*)&np_[m2 * 16 + grp * 4] = cacc[q2][m2];
      if (grp == 0) lb1[(bh << 11) + (rowg - 2048)] = lacc[q2][0];
    }
  }
}

// ---------------- Kernel 3: output projection + residual + LayerNorm (MFMA) ----------------
// Combines num slots: ctx_row = (num0 [+ num1]) * 1/(l0 [+ l1]), built as bf16 B-frags.
__global__ __launch_bounds__(256, 4) void oproj_ln(
    const float* __restrict__ num0, const float* __restrict__ num1,
    const float* __restrict__ lb0, const float* __restrict__ lb1,
    const unsigned short* __restrict__ Wot,
    const float* __restrict__ bo, const float* __restrict__ query,
    const float* __restrict__ gamma, const float* __restrict__ beta,
    float* __restrict__ out)
{
  __shared__ __align__(16) float redS[32][4];
  __shared__ __align__(16) float redQ[32][4];

  const int t = threadIdx.x;
  const int w = t >> 6, l = t & 63, lr = l & 15, grp = l >> 4;
  const long r0 = (long)blockIdx.x * 32;
  const int n0c = w * 64;
  const int b = (int)(r0 >> 12);
  const bool heavy = ((r0 >> 11) & 1) != 0;   // rows 2048..4095 within each b

  float invl[2][4];
  #pragma unroll
  for (int mt = 0; mt < 2; ++mt) {
    const int grow = (int)r0 + mt * 16 + lr;
    #pragma unroll
    for (int h = 0; h < 4; ++h) {
      float lv = lb0[((b * 4 + h) << 12) + (grow & 4095)];
      if (heavy) lv += lb1[((b * 4 + h) << 11) + (grow & 2047)];
      invl[mt][h] = 1.0f / lv;
    }
  }

  f32x4 acc[2][4] = {};

  #pragma unroll
  for (int k0 = 0; k0 < 256; k0 += 32) {
    s16x8 bfr[2];
    #pragma unroll
    for (int mt = 0; mt < 2; ++mt) {
      const int grow = (int)r0 + mt * 16 + lr;
      const int c = k0 + grp * 8;
      const float* p0 = num0 + (size_t)grow * 256 + c;
      f32x4 a0 = *(const f32x4*)p0;
      f32x4 a1 = *(const f32x4*)(p0 + 4);
      if (heavy) {
        const float* p1 = num1 + ((size_t)((b << 11) + (grow & 2047))) * 256 + c;
        a0 += *(const f32x4*)p1;
        a1 += *(const f32x4*)(p1 + 4);
      }
      const float iv = invl[mt][k0 >> 6];
      a0 *= iv; a1 *= iv;
      union { u32 wd[4]; s16x8 v; } bb;
      bb.wd[0] = cvtpk(a0[0], a0[1]);
      bb.wd[1] = cvtpk(a0[2], a0[3]);
      bb.wd[2] = cvtpk(a1[0], a1[1]);
      bb.wd[3] = cvtpk(a1[2], a1[3]);
      bfr[mt] = bb.v;
    }
    #pragma unroll
    for (int nt = 0; nt < 4; ++nt) {
      s16x8 af = *(const s16x8*)(Wot + (size_t)(n0c + nt * 16 + lr) * 256 + k0 + grp * 8);
      acc[0][nt] = __builtin_amdgcn_mfma_f32_16x16x32_bf16(af, bfr[0], acc[0][nt], 0, 0, 0);
      acc[1][nt] = __builtin_amdgcn_mfma_f32_16x16x32_bf16(af, bfr[1], acc[1][nt], 0, 0, 0);
    }
  }

  float sm[2] = {0.f, 0.f}, sq[2] = {0.f, 0.f};
  #pragma unroll
  for (int mt = 0; mt < 2; ++mt) {
    const long s = r0 + mt * 16 + lr;
    #pragma unroll
    for (int nt = 0; nt < 4; ++nt) {
      const int n = n0c + nt * 16 + grp * 4;
      f32x4 v = acc[mt][nt] + *(const f32x4*)&bo[n] + *(const f32x4*)&query[s * 256 + n];
      acc[mt][nt] = v;
      sm[mt] += v[0] + v[1] + v[2] + v[3];
      sq[mt] += v[0]*v[0] + v[1]*v[1] + v[2]*v[2] + v[3]*v[3];
    }
    sm[mt] += __shfl_xor(sm[mt], 16); sm[mt] += __shfl_xor(sm[mt], 32);
    sq[mt] += __shfl_xor(sq[mt], 16); sq[mt] += __shfl_xor(sq[mt], 32);
  }
  if (grp == 0) {
    redS[0 * 16 + lr][w] = sm[0]; redQ[0 * 16 + lr][w] = sq[0];
    redS[1 * 16 + lr][w] = sm[1]; redQ[1 * 16 + lr][w] = sq[1];
  }
  __syncthreads();

  #pragma unroll
  for (int mt = 0; mt < 2; ++mt) {
    f32x4 s4 = *(const f32x4*)&redS[mt * 16 + lr][0];
    f32x4 q4 = *(const f32x4*)&redQ[mt * 16 + lr][0];
    const float tot = s4[0] + s4[1] + s4[2] + s4[3];
    const float tq  = q4[0] + q4[1] + q4[2] + q4[3];
    const float mu  = tot * 0.00390625f;
    const float var = tq * 0.00390625f - mu * mu;
    const float rs  = rsqrtf(var + 1.0e-3f);
    const long s = r0 + mt * 16 + lr;
    #pragma unroll
    for (int nt = 0; nt < 4; ++nt) {
      const int n = n0c + nt * 16 + grp * 4;
      f32x4 g = *(const f32x4*)&gamma[n];
      f32x4 bt = *(const f32x4*)&beta[n];
      f32x4 o = (acc[mt][nt] - mu) * rs * g + bt;
      *(f32x4*)&out[s * 256 + n] = o;
    }
  }
}

extern "C" void kernel_launch(void* const* d_in, const int* in_sizes, int n_in,
                              void* d_out, int out_size, void* d_ws, size_t ws_size,
                              hipStream_t stream) {
  const float* query = (const float*)d_in[0];
  const float* value = (const float*)d_in[1];
  const float* Wq    = (const float*)d_in[2];
  const float* bq    = (const float*)d_in[3];
  const float* Wk    = (const float*)d_in[4];
  const float* bk    = (const float*)d_in[5];
  const float* Wv    = (const float*)d_in[6];
  const float* bv    = (const float*)d_in[7];
  const float* Wo    = (const float*)d_in[8];
  const float* bo    = (const float*)d_in[9];
  const float* gamma = (const float*)d_in[10];
  const float* beta  = (const float*)d_in[11];
  float* out = (float*)d_out;

  char* ws = (char*)d_ws;
  unsigned short* qb   = (unsigned short*)ws;                         //  8 MiB bf16 [bh][s][dk]
  unsigned short* kbs  = (unsigned short*)(ws + ((size_t)8  << 20));  //  8 MiB bf16 chunked K
  unsigned short* vts  = (unsigned short*)(ws + ((size_t)16 << 20));  //  8 MiB bf16 chunked V^T
  float* num0          = (float*)(ws + ((size_t)24 << 20));           // 16 MiB f32 [b*4096][256]
  float* num1          = (float*)(ws + ((size_t)40 << 20));           //  8 MiB f32 [b*2048][256] (heavy rows)
  float* lb0           = (float*)(ws + ((size_t)48 << 20));           // 256 KiB f32 [16][4096]
  float* lb1           = (float*)(ws + ((size_t)48 << 20) + ((size_t)256 << 10)); // 128 KiB f32 [16][2048]
  unsigned short* Wt   = (unsigned short*)(ws + ((size_t)48 << 20) + ((size_t)512 << 10)); // 384 KiB
  unsigned short* Wot  = Wt + (size_t)768 * 256;                      // 128 KiB

  wprep<<<64, 256, 0, stream>>>(Wq, Wk, Wv, Wo, Wt, Wot);
  qkv_mfma<<<512, 384, 0, stream>>>(query, value, Wt, bq, bk, bv, qb, kbs, vts);
  attn<<<512, 256, 0, stream>>>(qb, kbs, vts, num0, num1, lb0, lb1);
  oproj_ln<<<512, 256, 0, stream>>>(num0, num1, lb0, lb1, Wot, bo, query, gamma, beta, out);
}

// Round 10
// 109.106 us; speedup vs baseline: 1.3384x; 1.2753x over previous
//
#include <hip/hip_runtime.h>
#include <hip/hip_bf16.h>
#include <stdint.h>

#define SS 4096
#define DD 256
#define HH 4
#define KK 64
#define ALPHA 0.18033688011112042f  // 0.125 * log2(e)

typedef float f32x4 __attribute__((ext_vector_type(4)));
typedef short s16x8 __attribute__((ext_vector_type(8)));
typedef unsigned int u32;

__device__ __forceinline__ unsigned short f2bf(float x) {
  union { float f; unsigned u; } v; v.f = x;
  unsigned r = v.u + 0x7fffu + ((v.u >> 16) & 1u);
  return (unsigned short)(r >> 16);
}

__device__ __forceinline__ u32 cvtpk(float lo, float hi) {
  u32 r;
  asm("v_cvt_pk_bf16_f32 %0, %1, %2" : "=v"(r) : "v"(lo), "v"(hi));
  return r;
}

// hardware 2^x via compiler intrinsic (hazard-safe, single v_exp_f32)
#define fexp2(x) __builtin_amdgcn_exp2f(x)

__device__ __forceinline__ void gl_lds16(const unsigned short* g, unsigned short* l) {
  __builtin_amdgcn_global_load_lds(
      (const __attribute__((address_space(1))) u32*)g,
      (__attribute__((address_space(3))) u32*)l, 16, 0, 0);
}

// ---------------- Kernel 0: weight prep ----------------
__global__ void wprep(const float* __restrict__ Wq, const float* __restrict__ Wk,
                      const float* __restrict__ Wv, const float* __restrict__ Wo,
                      unsigned short* __restrict__ Wt, unsigned short* __restrict__ Wot)
{
  const int blk = blockIdx.x, t = threadIdx.x;
  const int rsub = t >> 4;
  const int c0 = (t & 15) * 16;
  if (blk < 48) {
    const int n = blk * 16 + rsub;               // 0..767
    const float* W = (n < 256) ? Wq : ((n < 512) ? Wk : Wv);
    const int nn = n & 255;
    const float sc = (n < 256) ? ALPHA : 1.0f;
    for (int c = c0; c < c0 + 16; ++c)
      Wt[(size_t)n * 256 + c] = f2bf(sc * W[(size_t)c * 256 + nn]);
  } else {
    const int d = (blk - 48) * 16 + rsub;        // 0..255
    for (int c = c0; c < c0 + 16; ++c)
      Wot[(size_t)d * 256 + c] = f2bf(Wo[(size_t)c * 256 + d]);
  }
}

// ---------------- Kernel 1: QKV projection (bf16 MFMA, LDS-staged X) ----------------
// 768 blocks x 256 thr: mat = blk%3 (0=Q,1=K,2=V), rb = blk/3 -> rows [rb*64, rb*64+64).
// X rows staged ONCE as bf16 into XOR-swizzled LDS (conversion deduplicated);
// wave w computes cols [w*64, w*64+64) (= head w), 4x4 frag tile, 128 MFMA/wave.
__global__ __launch_bounds__(256, 3) void qkv_mfma(
    const float* __restrict__ query, const float* __restrict__ value,
    const unsigned short* __restrict__ Wt,
    const float* __restrict__ bq, const float* __restrict__ bk,
    const float* __restrict__ bv,
    unsigned short* __restrict__ qb, unsigned short* __restrict__ kbs,
    unsigned short* __restrict__ vts)
{
  __shared__ __align__(16) unsigned short Xs[64 * 256];   // 32 KB, swizzled

  const int t = threadIdx.x;
  const int w = t >> 6, l = t & 63, lr = l & 15, grp = l >> 4;
  const int mat = (int)(blockIdx.x % 3u);
  const int rb  = (int)(blockIdx.x / 3u);
  const long r0 = (long)rb * 64;

  const float* X = (mat == 0) ? query : value;

  // stage: thread t -> row t>>2, col quarter (t&3)*64; swizzle idx ^= (row&7)<<3
  {
    const int row = t >> 2;
    const int c0s = (t & 3) * 64;
    const float* xp = X + (r0 + row) * 256 + c0s;
    const int sw = (row & 7) << 3;
    #pragma unroll
    for (int g = 0; g < 8; ++g) {
      f32x4 x0 = *(const f32x4*)(xp + g * 8);
      f32x4 x1 = *(const f32x4*)(xp + g * 8 + 4);
      union { u32 wd[4]; s16x8 v; } bb;
      bb.wd[0] = cvtpk(x0[0], x0[1]);
      bb.wd[1] = cvtpk(x0[2], x0[3]);
      bb.wd[2] = cvtpk(x1[0], x1[1]);
      bb.wd[3] = cvtpk(x1[2], x1[3]);
      *(s16x8*)&Xs[(row * 256 + c0s + g * 8) ^ sw] = bb.v;
    }
  }
  __syncthreads();

  const int n0 = w * 64;                 // head w
  const int swr = (lr & 7) << 3;

  f32x4 acc[4][4] = {};                  // [mt (s-block)][nt (n-block)]

  #pragma unroll 2
  for (int k0 = 0; k0 < 256; k0 += 32) {
    s16x8 xf[4];
    #pragma unroll
    for (int mt = 0; mt < 4; ++mt)
      xf[mt] = *(const s16x8*)&Xs[((mt * 16 + lr) * 256 + k0 + grp * 8) ^ swr];
    #pragma unroll
    for (int nt = 0; nt < 4; ++nt) {
      s16x8 af = *(const s16x8*)(Wt + (size_t)(mat * 256 + n0 + nt * 16 + lr) * 256 + k0 + grp * 8);
      if (mat == 2) {
        #pragma unroll
        for (int mt = 0; mt < 4; ++mt)
          acc[mt][nt] = __builtin_amdgcn_mfma_f32_16x16x32_bf16(xf[mt], af, acc[mt][nt], 0, 0, 0);
      } else {
        #pragma unroll
        for (int mt = 0; mt < 4; ++mt)
          acc[mt][nt] = __builtin_amdgcn_mfma_f32_16x16x32_bf16(af, xf[mt], acc[mt][nt], 0, 0, 0);
      }
    }
  }

  const int b  = (int)(r0 >> 12);
  const int s0 = (int)(r0 & 4095);
  const int kt = s0 >> 6;
  const size_t base = (size_t)(b * 4 + w) * (SS * KK) + (size_t)kt * 4096;

  if (mat == 0) {
    // D[n][s]: lane col = s = s0+mt*16+lr; rows n = n0+nt*16+grp*4+e
    #pragma unroll
    for (int nt = 0; nt < 4; ++nt) {
      const int nk = nt * 16 + grp * 4;
      f32x4 bias = *(const f32x4*)&bq[n0 + nk] * ALPHA;
      #pragma unroll
      for (int mt = 0; mt < 4; ++mt) {
        const int s = s0 + mt * 16 + lr;
        f32x4 o = acc[mt][nt] + bias;
        uint2 pk2; pk2.x = cvtpk(o[0], o[1]); pk2.y = cvtpk(o[2], o[3]);
        *(uint2*)&qb[((size_t)(b * 4 + w) * SS + s) * KK + nk] = pk2;
      }
    }
  } else if (mat == 1) {
    // K chunked: kv = mt*16+lr; d0 = nt*16+grp*4(+e)
    #pragma unroll
    for (int nt = 0; nt < 4; ++nt) {
      const int d0 = nt * 16 + grp * 4;
      const int cc = d0 >> 5, grpk = (d0 >> 3) & 3, jlo = d0 & 7;
      f32x4 bias = *(const f32x4*)&bk[n0 + d0];
      #pragma unroll
      for (int mt = 0; mt < 4; ++mt) {
        const int chunk = ((mt * 2 + cc) * 4 + grpk) * 16 + lr;
        f32x4 o = acc[mt][nt] + bias;
        uint2 pk2; pk2.x = cvtpk(o[0], o[1]); pk2.y = cvtpk(o[2], o[3]);
        *(uint2*)&kbs[base + chunk * 8 + jlo] = pk2;
      }
    }
  } else {
    // V chunked: D[s][n]: lane col = n = n0+nt*16+lr; rows s -> kv = mt*16+grp*4+e
    #pragma unroll
    for (int nt = 0; nt < 4; ++nt) {
      const float bvn = bv[n0 + nt * 16 + lr];
      #pragma unroll
      for (int mt = 0; mt < 4; ++mt) {
        const int cb = (nt * 2 + (mt >> 1)) * 64 + grp * 16 + lr;
        f32x4 o = acc[mt][nt] + bvn;
        uint2 pk2; pk2.x = cvtpk(o[0], o[1]); pk2.y = cvtpk(o[2], o[3]);
        *(uint2*)&vts[base + (size_t)cb * 8 + (mt & 1) * 4] = pk2;
      }
    }
  }
}

// ---------------- Kernel 2: causal flash attention (KV-split, exact balance) ----------------
// 512 blocks x 256 thr (4 waves x 32 q-rows). bh = i&15, pr = (i>>4)&15, role = i>>8.
// role 0 (light): supertile pr complete then supertile 31-pr tiles [0, 31-2pr).
// role 1 (heavy): supertile 31-pr tiles [31-2pr, 64-2pr). 33 tile-steps/block.
// Fixed-max softmax P=exp2(s-16) via __builtin_amdgcn_exp2f; l via ones-MFMA.
__global__ __launch_bounds__(256, 2) void attn(
    const unsigned short* __restrict__ qb,
    const unsigned short* __restrict__ kbs,
    const unsigned short* __restrict__ vts,
    float* __restrict__ num0, float* __restrict__ num1,
    float* __restrict__ lb0, float* __restrict__ lb1)
{
  __shared__ __align__(16) unsigned short Kl[2][4096];
  __shared__ __align__(16) unsigned short Vl[2][4096];

  const int t = threadIdx.x;
  const int w = t >> 6, l = t & 63, lr = l & 15, grp = l >> 4;

  const int i    = blockIdx.x;
  const int bh   = i & 15;
  const int pr   = (i >> 4) & 15;
  const int role = i >> 8;
  const int b = bh >> 2, h = bh & 3;
  const int phA_last = 2 * pr + 1;

  const unsigned short* kbase = kbs + (size_t)bh * (SS * KK);
  const unsigned short* vbase = vts + (size_t)bh * (SS * KK);
  const unsigned short* qpb   = qb  + (size_t)bh * (SS * KK);

  int sup = (role == 0) ? pr : (31 - pr);

  s16x8 qf[2][2];
  #pragma unroll
  for (int q2 = 0; q2 < 2; ++q2) {
    const unsigned short* qp = qpb + (size_t)(sup * 128 + w * 32 + q2 * 16 + lr) * KK;
    qf[q2][0] = *(const s16x8*)(qp + grp * 8);
    qf[q2][1] = *(const s16x8*)(qp + 32 + grp * 8);
  }

  s16x8 ones;
  #pragma unroll
  for (int e = 0; e < 8; ++e) ones[e] = (short)0x3F80;   // bf16 1.0
  const f32x4 minit = {-16.f, -16.f, -16.f, -16.f};

  f32x4 cacc[2][4] = {};
  f32x4 lacc[2] = {};

  const int off0 = (w * 64 + l) * 8;
  const int off1 = ((4 + w) * 64 + l) * 8;

  {
    const int kt0 = (role == 0) ? 0 : (31 - 2 * pr);
    const unsigned short* ks = kbase + (size_t)kt0 * 4096;
    const unsigned short* vs = vbase + (size_t)kt0 * 4096;
    gl_lds16(ks + off0, &Kl[0][w * 512]);
    gl_lds16(ks + off1, &Kl[0][(4 + w) * 512]);
    gl_lds16(vs + off0, &Vl[0][w * 512]);
    gl_lds16(vs + off1, &Vl[0][(4 + w) * 512]);
  }
  __syncthreads();

  for (int ss = 0; ss <= 32; ++ss) {
    const int cur = ss & 1;
    const int kt = (role == 0)
        ? ((ss <= phA_last) ? ss : (ss - (phA_last + 1)))
        : (31 - 2 * pr + ss);

    if (ss < 32) {
      const int ktn = (role == 0)
          ? ((ss + 1 <= phA_last) ? (ss + 1) : (ss + 1 - (phA_last + 1)))
          : (31 - 2 * pr + ss + 1);
      const unsigned short* ks = kbase + (size_t)ktn * 4096;
      const unsigned short* vs = vbase + (size_t)ktn * 4096;
      unsigned short* Kd = &Kl[cur ^ 1][0];
      unsigned short* Vd = &Vl[cur ^ 1][0];
      gl_lds16(ks + off0, Kd + w * 512);
      gl_lds16(ks + off1, Kd + (4 + w) * 512);
      gl_lds16(vs + off0, Vd + w * 512);
      gl_lds16(vs + off1, Vd + (4 + w) * 512);
    }

    if (!(kt == 2 * sup + 1 && w < 2)) {
      const unsigned short* Kb = &Kl[cur][0];
      const unsigned short* Vb = &Vl[cur][0];

      s16x8 kf[8];
      #pragma unroll
      for (int kc = 0; kc < 8; ++kc)
        kf[kc] = *(const s16x8*)&Kb[((kc * 4 + grp) * 16 + lr) * 8];

      f32x4 sc[2][4];
      #pragma unroll
      for (int q2 = 0; q2 < 2; ++q2) {
        #pragma unroll
        for (int kvt = 0; kvt < 4; ++kvt) {
          f32x4 a = __builtin_amdgcn_mfma_f32_16x16x32_bf16(kf[kvt * 2 + 0], qf[q2][0], minit, 0, 0, 0);
          a = __builtin_amdgcn_mfma_f32_16x16x32_bf16(kf[kvt * 2 + 1], qf[q2][1], a, 0, 0, 0);
          sc[q2][kvt] = a;
        }
      }

      if (kt >= 2 * sup) {
        const int kvb0 = kt * 64;
        #pragma unroll
        for (int q2 = 0; q2 < 2; ++q2) {
          const int qrow = sup * 128 + w * 32 + q2 * 16 + lr;
          #pragma unroll
          for (int kvt = 0; kvt < 4; ++kvt)
            #pragma unroll
            for (int e = 0; e < 4; ++e)
              if ((kvb0 + kvt * 16 + grp * 4 + e) > qrow) sc[q2][kvt][e] += -1.0e9f;
        }
      }

      #pragma unroll
      for (int q2 = 0; q2 < 2; ++q2)
        #pragma unroll
        for (int kvt = 0; kvt < 4; ++kvt)
          #pragma unroll
          for (int e = 0; e < 4; ++e)
            sc[q2][kvt][e] = fexp2(sc[q2][kvt][e]);

      s16x8 pf[2][2];
      #pragma unroll
      for (int q2 = 0; q2 < 2; ++q2) {
        #pragma unroll
        for (int kap = 0; kap < 2; ++kap) {
          union { u32 wd[4]; s16x8 v; } pu;
          pu.wd[0] = cvtpk(sc[q2][2 * kap][0], sc[q2][2 * kap][1]);
          pu.wd[1] = cvtpk(sc[q2][2 * kap][2], sc[q2][2 * kap][3]);
          pu.wd[2] = cvtpk(sc[q2][2 * kap + 1][0], sc[q2][2 * kap + 1][1]);
          pu.wd[3] = cvtpk(sc[q2][2 * kap + 1][2], sc[q2][2 * kap + 1][3]);
          pf[q2][kap] = pu.v;
        }
      }

      #pragma unroll
      for (int m2 = 0; m2 < 4; ++m2) {
        #pragma unroll
        for (int kap = 0; kap < 2; ++kap) {
          s16x8 vfr = *(const s16x8*)&Vb[((m2 * 2 + kap) * 64 + l) * 8];
          cacc[0][m2] = __builtin_amdgcn_mfma_f32_16x16x32_bf16(vfr, pf[0][kap], cacc[0][m2], 0, 0, 0);
          cacc[1][m2] = __builtin_amdgcn_mfma_f32_16x16x32_bf16(vfr, pf[1][kap], cacc[1][m2], 0, 0, 0);
        }
      }
      #pragma unroll
      for (int q2 = 0; q2 < 2; ++q2) {
        lacc[q2] = __builtin_amdgcn_mfma_f32_16x16x32_bf16(ones, pf[q2][0], lacc[q2], 0, 0, 0);
        lacc[q2] = __builtin_amdgcn_mfma_f32_16x16x32_bf16(ones, pf[q2][1], lacc[q2], 0, 0, 0);
      }
    }

    if (role == 0 && ss == phA_last) {
      #pragma unroll
      for (int q2 = 0; q2 < 2; ++q2) {
        const int rowg = sup * 128 + w * 32 + q2 * 16 + lr;
        float* np_ = num0 + ((size_t)((b << 12) + rowg)) * 256 + h * 64;
        #pragma unroll
        for (int m2 = 0; m2 < 4; ++m2) {
          *(f32x4*)&np_[m2 * 16 + grp * 4] = cacc[q2][m2];
          cacc[q2][m2] = (f32x4){0.f, 0.f, 0.f, 0.f};
        }
        if (grp == 0) lb0[(bh << 12) + rowg] = lacc[q2][0];
        lacc[q2] = (f32x4){0.f, 0.f, 0.f, 0.f};
      }
      sup = 31 - pr;
      #pragma unroll
      for (int q2 = 0; q2 < 2; ++q2) {
        const unsigned short* qp = qpb + (size_t)(sup * 128 + w * 32 + q2 * 16 + lr) * KK;
        qf[q2][0] = *(const s16x8*)(qp + grp * 8);
        qf[q2][1] = *(const s16x8*)(qp + 32 + grp * 8);
      }
    }
    __syncthreads();
  }

  if (role == 0) {
    #pragma unroll
    for (int q2 = 0; q2 < 2; ++q2) {
      const int rowg = sup * 128 + w * 32 + q2 * 16 + lr;
      float* np_ = num0 + ((size_t)((b << 12) + rowg)) * 256 + h * 64;
      #pragma unroll
      for (int m2 = 0; m2 < 4; ++m2)
        *(f32x4*)&np_[m2 * 16 + grp * 4] = cacc[q2][m2];
      if (grp == 0) lb0[(bh << 12) + rowg] = lacc[q2][0];
    }
  } else {
    #pragma unroll
    for (int q2 = 0; q2 < 2; ++q2) {
      const int rowg = sup * 128 + w * 32 + q2 * 16 + lr;   // >= 2048
      float* np_ = num1 + ((size_t)((b << 11) + (rowg - 2048))) * 256 + h * 64;
      #pragma unroll
      for (int m2 = 0; m2 < 4; ++m2)
        *(f32x4*)&np_[m2 * 16 + grp * 4] = cacc[q2][m2];
      if (grp == 0) lb1[(bh << 11) + (rowg - 2048)] = lacc[q2][0];
    }
  }
}

// ---------------- Kernel 3: output projection + residual + LayerNorm (MFMA) ----------------
__global__ __launch_bounds__(256, 4) void oproj_ln(
    const float* __restrict__ num0, const float* __restrict__ num1,
    const float* __restrict__ lb0, const float* __restrict__ lb1,
    const unsigned short* __restrict__ Wot,
    const float* __restrict__ bo, const float* __restrict__ query,
    const float* __restrict__ gamma, const float* __restrict__ beta,
    float* __restrict__ out)
{
  __shared__ __align__(16) float redS[32][4];
  __shared__ __align__(16) float redQ[32][4];

  const int t = threadIdx.x;
  const int w = t >> 6, l = t & 63, lr = l & 15, grp = l >> 4;
  const long r0 = (long)blockIdx.x * 32;
  const int n0c = w * 64;
  const int b = (int)(r0 >> 12);
  const bool heavy = ((r0 >> 11) & 1) != 0;

  float invl[2][4];
  #pragma unroll
  for (int mt = 0; mt < 2; ++mt) {
    const int grow = (int)r0 + mt * 16 + lr;
    #pragma unroll
    for (int h = 0; h < 4; ++h) {
      float lv = lb0[((b * 4 + h) << 12) + (grow & 4095)];
      if (heavy) lv += lb1[((b * 4 + h) << 11) + (grow & 2047)];
      invl[mt][h] = 1.0f / lv;
    }
  }

  f32x4 acc[2][4] = {};

  #pragma unroll
  for (int k0 = 0; k0 < 256; k0 += 32) {
    s16x8 bfr[2];
    #pragma unroll
    for (int mt = 0; mt < 2; ++mt) {
      const int grow = (int)r0 + mt * 16 + lr;
      const int c = k0 + grp * 8;
      const float* p0 = num0 + (size_t)grow * 256 + c;
      f32x4 a0 = *(const f32x4*)p0;
      f32x4 a1 = *(const f32x4*)(p0 + 4);
      if (heavy) {
        const float* p1 = num1 + ((size_t)((b << 11) + (grow & 2047))) * 256 + c;
        a0 += *(const f32x4*)p1;
        a1 += *(const f32x4*)(p1 + 4);
      }
      const float iv = invl[mt][k0 >> 6];
      a0 *= iv; a1 *= iv;
      union { u32 wd[4]; s16x8 v; } bb;
      bb.wd[0] = cvtpk(a0[0], a0[1]);
      bb.wd[1] = cvtpk(a0[2], a0[3]);
      bb.wd[2] = cvtpk(a1[0], a1[1]);
      bb.wd[3] = cvtpk(a1[2], a1[3]);
      bfr[mt] = bb.v;
    }
    #pragma unroll
    for (int nt = 0; nt < 4; ++nt) {
      s16x8 af = *(const s16x8*)(Wot + (size_t)(n0c + nt * 16 + lr) * 256 + k0 + grp * 8);
      acc[0][nt] = __builtin_amdgcn_mfma_f32_16x16x32_bf16(af, bfr[0], acc[0][nt], 0, 0, 0);
      acc[1][nt] = __builtin_amdgcn_mfma_f32_16x16x32_bf16(af, bfr[1], acc[1][nt], 0, 0, 0);
    }
  }

  float sm[2] = {0.f, 0.f}, sq[2] = {0.f, 0.f};
  #pragma unroll
  for (int mt = 0; mt < 2; ++mt) {
    const long s = r0 + mt * 16 + lr;
    #pragma unroll
    for (int nt = 0; nt < 4; ++nt) {
      const int n = n0c + nt * 16 + grp * 4;
      f32x4 v = acc[mt][nt] + *(const f32x4*)&bo[n] + *(const f32x4*)&query[s * 256 + n];
      acc[mt][nt] = v;
      sm[mt] += v[0] + v[1] + v[2] + v[3];
      sq[mt] += v[0]*v[0] + v[1]*v[1] + v[2]*v[2] + v[3]*v[3];
    }
    sm[mt] += __shfl_xor(sm[mt], 16); sm[mt] += __shfl_xor(sm[mt], 32);
    sq[mt] += __shfl_xor(sq[mt], 16); sq[mt] += __shfl_xor(sq[mt], 32);
  }
  if (grp == 0) {
    redS[0 * 16 + lr][w] = sm[0]; redQ[0 * 16 + lr][w] = sq[0];
    redS[1 * 16 + lr][w] = sm[1]; redQ[1 * 16 + lr][w] = sq[1];
  }
  __syncthreads();

  #pragma unroll
  for (int mt = 0; mt < 2; ++mt) {
    f32x4 s4 = *(const f32x4*)&redS[mt * 16 + lr][0];
    f32x4 q4 = *(const f32x4*)&redQ[mt * 16 + lr][0];
    const float tot = s4[0] + s4[1] + s4[2] + s4[3];
    const float tq  = q4[0] + q4[1] + q4[2] + q4[3];
    const float mu  = tot * 0.00390625f;
    const float var = tq * 0.00390625f - mu * mu;
    const float rs  = rsqrtf(var + 1.0e-3f);
    const long s = r0 + mt * 16 + lr;
    #pragma unroll
    for (int nt = 0; nt < 4; ++nt) {
      const int n = n0c + nt * 16 + grp * 4;
      f32x4 g = *(const f32x4*)&gamma[n];
      f32x4 bt = *(const f32x4*)&beta[n];
      f32x4 o = (acc[mt][nt] - mu) * rs * g + bt;
      *(f32x4*)&out[s * 256 + n] = o;
    }
  }
}

extern "C" void kernel_launch(void* const* d_in, const int* in_sizes, int n_in,
                              void* d_out, int out_size, void* d_ws, size_t ws_size,
                              hipStream_t stream) {
  const float* query = (const float*)d_in[0];
  const float* value = (const float*)d_in[1];
  const float* Wq    = (const float*)d_in[2];
  const float* bq    = (const float*)d_in[3];
  const float* Wk    = (const float*)d_in[4];
  const float* bk    = (const float*)d_in[5];
  const float* Wv    = (const float*)d_in[6];
  const float* bv    = (const float*)d_in[7];
  const float* Wo    = (const float*)d_in[8];
  const float* bo    = (const float*)d_in[9];
  const float* gamma = (const float*)d_in[10];
  const float* beta  = (const float*)d_in[11];
  float* out = (float*)d_out;

  char* ws = (char*)d_ws;
  unsigned short* qb   = (unsigned short*)ws;                         //  8 MiB bf16 [bh][s][dk]
  unsigned short* kbs  = (unsigned short*)(ws + ((size_t)8  << 20));  //  8 MiB bf16 chunked K
  unsigned short* vts  = (unsigned short*)(ws + ((size_t)16 << 20));  //  8 MiB bf16 chunked V^T
  float* num0          = (float*)(ws + ((size_t)24 << 20));           // 16 MiB f32
  float* num1          = (float*)(ws + ((size_t)40 << 20));           //  8 MiB f32 (heavy rows)
  float* lb0           = (float*)(ws + ((size_t)48 << 20));           // 256 KiB f32
  float* lb1           = (float*)(ws + ((size_t)48 << 20) + ((size_t)256 << 10)); // 128 KiB
  unsigned short* Wt   = (unsigned short*)(ws + ((size_t)48 << 20) + ((size_t)512 << 10)); // 384 KiB
  unsigned short* Wot  = Wt + (size_t)768 * 256;                      // 128 KiB

  wprep<<<64, 256, 0, stream>>>(Wq, Wk, Wv, Wo, Wt, Wot);
  qkv_mfma<<<768, 256, 0, stream>>>(query, value, Wt, bq, bk, bv, qb, kbs, vts);
  attn<<<512, 256, 0, stream>>>(qb, kbs, vts, num0, num1, lb0, lb1);
  oproj_ln<<<512, 256, 0, stream>>>(num0, num1, lb0, lb1, Wot, bo, query, gamma, beta, out);
}